// Round 1
// baseline (19.288 us; speedup 1.0000x reference)
//
#include <hip/hip_runtime.h>
#include <hip/hip_bf16.h>

#define BB 8
#define VV 128
#define TT 512

__global__ __launch_bounds__(256)
void DiffGraphLearn_kernel(const float* __restrict__ x,
                           const float* __restrict__ w,
                           float* __restrict__ out) {
    const int blk  = blockIdx.x;          // b*VV + i
    const int b    = blk >> 7;
    const int i    = blk & (VV - 1);
    const int tid  = threadIdx.x;         // 0..255
    const int lane = tid & 63;
    const int wave = tid >> 6;            // 0..3

    __shared__ float xi[TT];
    __shared__ float ws[TT];
    __shared__ float scores[VV];

    const float* __restrict__ xb = x + (size_t)b * VV * TT;

    // Stage x[b,i,:] and w into LDS (vectorized: 512 floats = 128 float4, 256 threads)
    {
        const float4* xi_g = (const float4*)(xb + (size_t)i * TT);
        const float4* w_g  = (const float4*)w;
        float4* xi_s = (float4*)xi;
        float4* ws_s = (float4*)ws;
        if (tid < TT / 4) {
            xi_s[tid] = xi_g[tid];
            ws_s[tid] = w_g[tid];
        }
    }
    __syncthreads();

    // Each wave handles j = wave, wave+4, ...
    for (int j = wave; j < VV; j += 4) {
        const float4* __restrict__ xj = (const float4*)(xb + (size_t)j * TT);
        float acc = 0.f;
#pragma unroll
        for (int k = 0; k < 2; ++k) {
            const int idx = lane + 64 * k;   // float4 index; t = idx*4 .. idx*4+3
            float4 vx = xj[idx];
            float4 vi = ((const float4*)xi)[idx];
            float4 vw = ((const float4*)ws)[idx];
            acc += fabsf(vi.x - vx.x) * vw.x;
            acc += fabsf(vi.y - vx.y) * vw.y;
            acc += fabsf(vi.z - vx.z) * vw.z;
            acc += fabsf(vi.w - vx.w) * vw.w;
        }
        // 64-lane butterfly reduce
#pragma unroll
        for (int off = 32; off >= 1; off >>= 1)
            acc += __shfl_xor(acc, off, 64);
        if (lane == 0)
            scores[j] = fmaxf(acc, 0.f);     // ReLU
    }
    __syncthreads();

    // Row softmax over 128 scores: wave 0, 2 elems/lane
    if (wave == 0) {
        float s0 = scores[lane];
        float s1 = scores[lane + 64];
        float m = fmaxf(s0, s1);
#pragma unroll
        for (int off = 32; off >= 1; off >>= 1)
            m = fmaxf(m, __shfl_xor(m, off, 64));
        float e0 = __expf(s0 - m);
        float e1 = __expf(s1 - m);
        float s = e0 + e1;
#pragma unroll
        for (int off = 32; off >= 1; off >>= 1)
            s += __shfl_xor(s, off, 64);
        const float inv = __frcp_rn(s);
        float* __restrict__ o = out + (size_t)blk * VV;
        o[lane]      = e0 * inv;
        o[lane + 64] = e1 * inv;
    }
}

extern "C" void kernel_launch(void* const* d_in, const int* in_sizes, int n_in,
                              void* d_out, int out_size, void* d_ws, size_t ws_size,
                              hipStream_t stream) {
    const float* x = (const float*)d_in[0];   // [8,128,512] f32
    const float* w = (const float*)d_in[1];   // [512] f32
    float* out = (float*)d_out;               // [8,128,128] f32

    dim3 grid(BB * VV);   // 1024 blocks, one per (b, i) row
    dim3 block(256);
    hipLaunchKernelGGL(DiffGraphLearn_kernel, grid, block, 0, stream, x, w, out);
}

// Round 2
// 14.961 us; speedup vs baseline: 1.2892x; 1.2892x over previous
//
#include <hip/hip_runtime.h>
#include <hip/hip_bf16.h>

#define BB 8
#define VV 128
#define TT 512
#define ITILE 4     // i-rows per block
#define NWAVES 8    // 512 threads per block

__global__ __launch_bounds__(512)
void DiffGraphLearn_kernel(const float* __restrict__ x,
                           const float* __restrict__ w,
                           float* __restrict__ out) {
    const int blk  = blockIdx.x;           // b*32 + itile
    const int b    = blk >> 5;
    const int i0   = (blk & 31) * ITILE;
    const int tid  = threadIdx.x;
    const int lane = tid & 63;
    const int wave = tid >> 6;             // 0..7

    __shared__ float scores[ITILE][VV];

    const float* __restrict__ xb = x + (size_t)b * VV * TT;

    // Hoist w and the 4 xi rows into registers (lane <-> t mapping: float4
    // index lane and lane+64, i.e. t = 4*idx .. 4*idx+3).
    const float4* __restrict__ wf4 = (const float4*)w;
    const float4 w0 = wf4[lane];
    const float4 w1 = wf4[lane + 64];
    float4 xi0[ITILE], xi1[ITILE];
#pragma unroll
    for (int r = 0; r < ITILE; ++r) {
        const float4* xif = (const float4*)(xb + (size_t)(i0 + r) * TT);
        xi0[r] = xif[lane];
        xi1[r] = xif[lane + 64];
    }

    // j loop: wave handles j = wave + 8*s (16 iterations)
    for (int s = 0; s < VV / NWAVES; ++s) {
        const int j = wave + NWAVES * s;
        const float4* __restrict__ xj = (const float4*)(xb + (size_t)j * TT);
        const float4 a = xj[lane];
        const float4 c = xj[lane + 64];

        float acc[ITILE];
#pragma unroll
        for (int r = 0; r < ITILE; ++r) {
            float v = 0.f;
            v += fabsf(xi0[r].x - a.x) * w0.x;
            v += fabsf(xi0[r].y - a.y) * w0.y;
            v += fabsf(xi0[r].z - a.z) * w0.z;
            v += fabsf(xi0[r].w - a.w) * w0.w;
            v += fabsf(xi1[r].x - c.x) * w1.x;
            v += fabsf(xi1[r].y - c.y) * w1.y;
            v += fabsf(xi1[r].z - c.z) * w1.z;
            v += fabsf(xi1[r].w - c.w) * w1.w;
            acc[r] = v;
        }

        // Joint 4-value wave reduction: after this, lane k (k = lane&3)
        // holds the full 64-lane sum of acc[k].
        float t0k = (lane & 1) ? acc[1] : acc[0];
        float t0s = (lane & 1) ? acc[0] : acc[1];
        t0k += __shfl_xor(t0s, 1, 64);
        float t1k = (lane & 1) ? acc[3] : acc[2];
        float t1s = (lane & 1) ? acc[2] : acc[3];
        t1k += __shfl_xor(t1s, 1, 64);
        float vk = (lane & 2) ? t1k : t0k;
        float vs = (lane & 2) ? t0k : t1k;
        vk += __shfl_xor(vs, 2, 64);
#pragma unroll
        for (int off = 4; off <= 32; off <<= 1)
            vk += __shfl_xor(vk, off, 64);

        if (lane < ITILE)
            scores[lane][j] = fmaxf(vk, 0.f);   // ReLU at store
    }
    __syncthreads();

    // Row softmax: waves 0..3 each handle one of the 4 rows.
    if (wave < ITILE) {
        const float s0 = scores[wave][lane];
        const float s1 = scores[wave][lane + 64];
        float m = fmaxf(s0, s1);
#pragma unroll
        for (int off = 32; off >= 1; off >>= 1)
            m = fmaxf(m, __shfl_xor(m, off, 64));
        const float e0 = __expf(s0 - m);
        const float e1 = __expf(s1 - m);
        float sum = e0 + e1;
#pragma unroll
        for (int off = 32; off >= 1; off >>= 1)
            sum += __shfl_xor(sum, off, 64);
        const float inv = __frcp_rn(sum);
        float* __restrict__ o = out + ((size_t)b * VV + i0 + wave) * VV;
        o[lane]      = e0 * inv;
        o[lane + 64] = e1 * inv;
    }
}

extern "C" void kernel_launch(void* const* d_in, const int* in_sizes, int n_in,
                              void* d_out, int out_size, void* d_ws, size_t ws_size,
                              hipStream_t stream) {
    const float* x = (const float*)d_in[0];   // [8,128,512] f32
    const float* w = (const float*)d_in[1];   // [512] f32
    float* out = (float*)d_out;               // [8,128,128] f32

    dim3 grid(BB * (VV / ITILE));   // 8 * 32 = 256 blocks, one per CU
    dim3 block(NWAVES * 64);        // 512 threads
    hipLaunchKernelGGL(DiffGraphLearn_kernel, grid, block, 0, stream, x, w, out);
}

// Round 3
// 12.480 us; speedup vs baseline: 1.5454x; 1.1988x over previous
//
#include <hip/hip_runtime.h>
#include <hip/hip_bf16.h>

#define BB 8
#define VV 128
#define TT 512
#define ITILE 4      // i-rows per block
#define NWAVES 16    // 1024 threads per block -> 4 waves/SIMD

__global__ __launch_bounds__(1024)
void DiffGraphLearn_kernel(const float* __restrict__ x,
                           const float* __restrict__ w,
                           float* __restrict__ out) {
    const int blk  = blockIdx.x;           // b*32 + itile
    const int b    = blk >> 5;
    const int i0   = (blk & 31) * ITILE;
    const int tid  = threadIdx.x;
    const int lane = tid & 63;
    const int wave = tid >> 6;             // 0..15

    __shared__ float scores[ITILE][VV];

    const float* __restrict__ xb = x + (size_t)b * VV * TT;

    // Hoist w and the ITILE xi rows into registers (float4 index lane, lane+64).
    const float4* __restrict__ wf4 = (const float4*)w;
    const float4 w0 = wf4[lane];
    const float4 w1 = wf4[lane + 64];
    float4 xi0[ITILE], xi1[ITILE];
#pragma unroll
    for (int r = 0; r < ITILE; ++r) {
        const float4* xif = (const float4*)(xb + (size_t)(i0 + r) * TT);
        xi0[r] = xif[lane];
        xi1[r] = xif[lane + 64];
    }

    // j loop: wave handles j = wave + 16*s (8 iterations), software-pipelined.
    int j = wave;
    const float4* xjp = (const float4*)(xb + (size_t)j * TT);
    float4 a = xjp[lane];
    float4 c = xjp[lane + 64];

    for (int s = 0; s < VV / NWAVES; ++s) {
        // Prefetch next j's data while we compute/reduce the current one.
        float4 na, nc;
        if (s < VV / NWAVES - 1) {
            const float4* xn = (const float4*)(xb + (size_t)(j + NWAVES) * TT);
            na = xn[lane];
            nc = xn[lane + 64];
        }

        float acc[ITILE];
#pragma unroll
        for (int r = 0; r < ITILE; ++r) {
            float v = 0.f;
            v += fabsf(xi0[r].x - a.x) * w0.x;
            v += fabsf(xi0[r].y - a.y) * w0.y;
            v += fabsf(xi0[r].z - a.z) * w0.z;
            v += fabsf(xi0[r].w - a.w) * w0.w;
            v += fabsf(xi1[r].x - c.x) * w1.x;
            v += fabsf(xi1[r].y - c.y) * w1.y;
            v += fabsf(xi1[r].z - c.z) * w1.z;
            v += fabsf(xi1[r].w - c.w) * w1.w;
            acc[r] = v;
        }

        // Joint 4-value wave reduction: lane k (k = lane&3) ends with the
        // full 64-lane sum of acc[k].
        float t0k = (lane & 1) ? acc[1] : acc[0];
        float t0s = (lane & 1) ? acc[0] : acc[1];
        t0k += __shfl_xor(t0s, 1, 64);
        float t1k = (lane & 1) ? acc[3] : acc[2];
        float t1s = (lane & 1) ? acc[2] : acc[3];
        t1k += __shfl_xor(t1s, 1, 64);
        float vk = (lane & 2) ? t1k : t0k;
        float vs = (lane & 2) ? t0k : t1k;
        vk += __shfl_xor(vs, 2, 64);
#pragma unroll
        for (int off = 4; off <= 32; off <<= 1)
            vk += __shfl_xor(vk, off, 64);

        if (lane < ITILE)
            scores[lane][j] = fmaxf(vk, 0.f);   // ReLU at store

        j += NWAVES;
        a = na;
        c = nc;
    }
    __syncthreads();

    // Row softmax: waves 0..3 each handle one of the ITILE rows.
    if (wave < ITILE) {
        const float s0 = scores[wave][lane];
        const float s1 = scores[wave][lane + 64];
        float m = fmaxf(s0, s1);
#pragma unroll
        for (int off = 32; off >= 1; off >>= 1)
            m = fmaxf(m, __shfl_xor(m, off, 64));
        const float e0 = __expf(s0 - m);
        const float e1 = __expf(s1 - m);
        float sum = e0 + e1;
#pragma unroll
        for (int off = 32; off >= 1; off >>= 1)
            sum += __shfl_xor(sum, off, 64);
        const float inv = __frcp_rn(sum);
        float* __restrict__ o = out + ((size_t)b * VV + i0 + wave) * VV;
        o[lane]      = e0 * inv;
        o[lane + 64] = e1 * inv;
    }
}

extern "C" void kernel_launch(void* const* d_in, const int* in_sizes, int n_in,
                              void* d_out, int out_size, void* d_ws, size_t ws_size,
                              hipStream_t stream) {
    const float* x = (const float*)d_in[0];   // [8,128,512] f32
    const float* w = (const float*)d_in[1];   // [512] f32
    float* out = (float*)d_out;               // [8,128,128] f32

    dim3 grid(BB * (VV / ITILE));   // 256 blocks, one per CU
    dim3 block(NWAVES * 64);        // 1024 threads = 16 waves
    hipLaunchKernelGGL(DiffGraphLearn_kernel, grid, block, 0, stream, x, w, out);
}